// Round 7
// baseline (3387.801 us; speedup 1.0000x reference)
//
#include <hip/hip_runtime.h>

#define Bn 256
#define Tn 2048
#define Dn 40
#define Hn 128
#define Cn 35

typedef _Float16 h2 __attribute__((ext_vector_type(2)));

__device__ __forceinline__ int sdot4(int a, int b, int c) {
#if __has_builtin(__builtin_amdgcn_sdot4)
  return __builtin_amdgcn_sdot4(a, b, c, false);
#else
  int r = c;
#pragma unroll
  for (int i = 0; i < 4; ++i)
    r += ((int)(a << (24 - 8 * i)) >> 24) * ((int)(b << (24 - 8 * i)) >> 24);
  return r;
#endif
}

__device__ __forceinline__ float fdot2f(h2 a, h2 b, float c) {
#if __has_builtin(__builtin_amdgcn_fdot2)
  return __builtin_amdgcn_fdot2(a, b, c, false);
#else
  return c + (float)(a[0]) * (float)(b[0]) + (float)(a[1]) * (float)(b[1]);
#endif
}

__device__ __forceinline__ h2 bch(int u) { return __builtin_bit_cast(h2, u); }

__device__ __forceinline__ int pk2i(float a, float b) {  // two f16 in one word
  h2 r; r[0] = (_Float16)a; r[1] = (_Float16)b;
  return __builtin_bit_cast(int, r);
}

__device__ __forceinline__ float rcpf_(float x) {
#if __has_builtin(__builtin_amdgcn_rcpf)
  return __builtin_amdgcn_rcpf(x);
#else
  return 1.f / x;
#endif
}

__device__ __forceinline__ float sigm(float v) {
  v = fmaxf(fminf(v, 60.f), -60.f);
  return rcpf_(1.f + __expf(-v));
}

__device__ __forceinline__ float tanha(float v) {
  v = fmaxf(fminf(v, 15.f), -15.f);
  const float e = __expf(2.f * v);
  return (e - 1.f) * rcpf_(e + 1.f);
}

__device__ __forceinline__ int q8c(float v) {  // round+clamp to [-127,127]
  v = fminf(fmaxf(v, -127.f), 127.f);
  return (int)__builtin_rintf(v);
}

__device__ __forceinline__ int pk4(int a, int b, int c, int d) {
  return (a & 255) | ((b & 255) << 8) | ((c & 255) << 16) | (d << 24);
}

__device__ __forceinline__ float bperm_f(int byte_idx, float v) {
  return __builtin_bit_cast(
      float, __builtin_amdgcn_ds_bpermute(byte_idx, __builtin_bit_cast(int, v)));
}

#if __has_builtin(__builtin_amdgcn_global_load_lds)
#define HAVE_GLDS 1
__device__ __forceinline__ void gl_lds16(const float* g, float* l) {
  __builtin_amdgcn_global_load_lds(
      (const __attribute__((address_space(1))) unsigned int*)(const void*)g,
      (__attribute__((address_space(3))) unsigned int*)(void*)l, 16, 0, 0);
}
#endif

// quantize 128 f32 weights -> 32 packed-i8 words + scale (rowmax/127)
__device__ __forceinline__ void quantW128(const float* __restrict__ p,
                                          int* __restrict__ q, float& sc) {
  float m = 1e-30f;
#pragma unroll
  for (int i = 0; i < 32; ++i) {
    const float4 v = reinterpret_cast<const float4*>(p)[i];
    m = fmaxf(m, fmaxf(fmaxf(fabsf(v.x), fabsf(v.y)),
                       fmaxf(fabsf(v.z), fabsf(v.w))));
  }
  const float inv = 127.f / m;
  sc = m * (1.f / 127.f);
#pragma unroll
  for (int i = 0; i < 32; ++i) {
    const float4 v = reinterpret_cast<const float4*>(p)[i];
    q[i] = pk4(q8c(v.x * inv), q8c(v.y * inv), q8c(v.z * inv), q8c(v.w * inv));
  }
}

// readlane word w (0..319) from 5-reg stash (lane L holds flat[L+64k])
#define RLST(w) __builtin_amdgcn_readlane(                                  \
    ((w) < 64 ? st0 : (w) < 128 ? st1 : (w) < 192 ? st2 : (w) < 256 ? st3  \
                                                        : st4), (w) & 63)

// Measured laws r1-r6: (1) 65,536 VGPRs per WG total -> i8 weights in regs.
// (2) each barrier-phase costs ~700-750 cy (r1 3 bar = 3660 cy/step, r6 2
// bar = 2940; VALU issue only ~1030) -> the floor is phase count, not
// instructions. r7: ONE barrier/step. Gate remap: lane 4q+g of wave w owns
// gate g of column u=16w+q for BOTH layers (weight row 128g+u). After the
// dot stream the 4 gates of a column live in one lane-quad -> collect via
// 8 ds_bpermute (in-wave), update c0/c1 redundantly in-quad, write h as i8
// bytes to a parity-double-buffered stash. No U phase, no s_p round trip.
// All quantization arithmetic is kept bit-identical to r6 (int dots exact,
// same float association) -> absmax must equal 0.03027344.
__global__ __launch_bounds__(512) void lstm2_fused(
    const float* __restrict__ x,
    const int*   __restrict__ length,
    const float* __restrict__ Wih0, const float* __restrict__ Whh0,
    const float* __restrict__ bih0, const float* __restrict__ bhh0,
    const float* __restrict__ Wih1, const float* __restrict__ Whh1,
    const float* __restrict__ bih1, const float* __restrict__ bhh1,
    const float* __restrict__ gam,  const float* __restrict__ bet,
    const float* __restrict__ fcw,  const float* __restrict__ fcb,
    float* __restrict__ out)
{
  __shared__ int   s_w0x[20][512];                 // 40 KiB w0x f16-pairs SoA
  __shared__ __align__(16) float s_xraw[192 * 4];  // 3 KiB raw x chunk (glds dest)
  __shared__ int   s_xh2[2][320];                  // 2.5 KiB f16 x chunks
  __shared__ float s_xp[2][16][512];               // 64 KiB x-projection
  __shared__ int   s_hq[2][64];                    // parity-buffered i8 h stash
  __shared__ float s_h1f[128];
  __shared__ float s_hn[128];

  const int tid  = threadIdx.x;
  const int lane = tid & 63;
  const int wav  = tid >> 6;
  const int g    = lane & 3;                // gate index: 0=i 1=f 2=g 3=o
  const int u    = 16 * wav + (lane >> 2);  // column 0..127
  const int row  = 128 * g + u;             // weight/bias row 0..511
  const int b    = blockIdx.x;
  const int len  = length[b];  // 1..2048

  // ---- kick off chunk-0 x prefetch (hidden under weight setup) ----
  if (tid >= 256 && tid < 448) {
    const int seg0 = (tid >> 6) - 4;  // wave segment 0..2
    int seg = seg0 * 64 + lane;
    if (seg >= 160) seg = 0;  // clamp (writes land in unused s_xraw tail)
#if HAVE_GLDS
    gl_lds16(x + (size_t)b * Tn * Dn + seg * 4, &s_xraw[seg0 * 256]);
#else
    *(float4*)&s_xraw[seg * 4] =
        *(const float4*)(x + (size_t)b * Tn * Dn + seg * 4);
#endif
  }

  // ---- weight setup (all rows indexed by `row`) ----
  int q0h[32], q1x[32], q1h[32];
  float s0h, s1x, s1h;
  quantW128(Whh0 + (size_t)row * Hn, q0h, s0h);
  quantW128(Wih1 + (size_t)row * Hn, q1x, s1x);
  quantW128(Whh1 + (size_t)row * Hn, q1h, s1h);
  s0h *= (1.f / 127.f);  // fold fixed h-scale
  s1x *= (1.f / 127.f);
  s1h *= (1.f / 127.f);
  {  // w0x row -> LDS f16 pairs (burst consumer is thread tid itself)
    const float* p = Wih0 + (size_t)row * Dn;
#pragma unroll
    for (int k = 0; k < 20; ++k) s_w0x[k][tid] = pk2i(p[2 * k], p[2 * k + 1]);
  }
  const float bias0 = bih0[row] + bhh0[row];
  const float bias1 = bih1[row] + bhh1[row];

  float c0 = 0.f;  // quad-redundant L0 cell state of column u
  float c1 = 0.f;  // quad-redundant L1 cell state of column u

  if (tid < 128) ((int*)s_hq)[tid] = 0;  // both parity buffers = 0
  __syncthreads();  // glds drained; s_w0x visible

  // x-projection burst: s_xh2[bb] -> s_xp[bb] (4 passes x 4 rows caps regs)
  auto burst = [&](int bb) {
    const int* flat = &s_xh2[bb][0];
    const int st0 = flat[lane], st1 = flat[lane + 64], st2 = flat[lane + 128],
              st3 = flat[lane + 192], st4 = flat[lane + 256];
#pragma unroll
    for (int pass = 0; pass < 4; ++pass) {
      float a0 = 0.f, a1 = 0.f, a2 = 0.f, a3 = 0.f;
      const int r0 = pass * 4;
#pragma unroll
      for (int gg = 0; gg < 5; ++gg) {
        const h2 w0 = bch(s_w0x[4 * gg + 0][tid]);
        const h2 w1 = bch(s_w0x[4 * gg + 1][tid]);
        const h2 w2 = bch(s_w0x[4 * gg + 2][tid]);
        const h2 w3 = bch(s_w0x[4 * gg + 3][tid]);
        a0 = fdot2f(bch(RLST(20 * (r0 + 0) + 4 * gg + 0)), w0, a0);
        a0 = fdot2f(bch(RLST(20 * (r0 + 0) + 4 * gg + 1)), w1, a0);
        a0 = fdot2f(bch(RLST(20 * (r0 + 0) + 4 * gg + 2)), w2, a0);
        a0 = fdot2f(bch(RLST(20 * (r0 + 0) + 4 * gg + 3)), w3, a0);
        a1 = fdot2f(bch(RLST(20 * (r0 + 1) + 4 * gg + 0)), w0, a1);
        a1 = fdot2f(bch(RLST(20 * (r0 + 1) + 4 * gg + 1)), w1, a1);
        a1 = fdot2f(bch(RLST(20 * (r0 + 1) + 4 * gg + 2)), w2, a1);
        a1 = fdot2f(bch(RLST(20 * (r0 + 1) + 4 * gg + 3)), w3, a1);
        a2 = fdot2f(bch(RLST(20 * (r0 + 2) + 4 * gg + 0)), w0, a2);
        a2 = fdot2f(bch(RLST(20 * (r0 + 2) + 4 * gg + 1)), w1, a2);
        a2 = fdot2f(bch(RLST(20 * (r0 + 2) + 4 * gg + 2)), w2, a2);
        a2 = fdot2f(bch(RLST(20 * (r0 + 2) + 4 * gg + 3)), w3, a2);
        a3 = fdot2f(bch(RLST(20 * (r0 + 3) + 4 * gg + 0)), w0, a3);
        a3 = fdot2f(bch(RLST(20 * (r0 + 3) + 4 * gg + 1)), w1, a3);
        a3 = fdot2f(bch(RLST(20 * (r0 + 3) + 4 * gg + 2)), w2, a3);
        a3 = fdot2f(bch(RLST(20 * (r0 + 3) + 4 * gg + 3)), w3, a3);
      }
      s_xp[bb][r0 + 0][tid] = a0;
      s_xp[bb][r0 + 1][tid] = a1;
      s_xp[bb][r0 + 2][tid] = a2;
      s_xp[bb][r0 + 3][tid] = a3;
    }
  };

  // ---- chunk 0: convert to f16, project ----
  if (tid >= 256 && tid < 416) {
    const int uu = tid - 256;  // 0..159
    const float4 v = *(const float4*)&s_xraw[4 * uu];
    s_xh2[0][2 * uu]     = pk2i(v.x, v.y);
    s_xh2[0][2 * uu + 1] = pk2i(v.z, v.w);
  }
  __syncthreads();
  burst(0);
  __syncthreads();

  const int pb = (lane & ~3) << 2;  // bpermute byte base of this quad

#pragma unroll 1
  for (int t = 0; t <= len; ++t) {  // phase t: L0 step t, L1 step t-1
    const int tl = t & 15;

    const int vq = s_hq[t & 1][lane];  // h0(t-1) words 0-31 | h1(t-2) words 32-63

    if (tid >= 256 && tid < 448 && tl == 12) {  // async prefetch next raw x
      const int t0 = (t & ~15) + 16;
      if (t0 <= Tn - 16) {
        const int seg0 = (tid >> 6) - 4;
        int seg = seg0 * 64 + lane;
        if (seg >= 160) seg = 0;
#if HAVE_GLDS
        gl_lds16(x + ((size_t)b * Tn + t0) * Dn + seg * 4,
                 &s_xraw[seg0 * 256]);
#else
        *(float4*)&s_xraw[seg * 4] =
            *(const float4*)(x + ((size_t)b * Tn + t0) * Dn + seg * 4);
#endif
      }
    } else if (tid >= 256 && tid < 416 && tl == 13) {
      // convert raw chunk (rows t+3 .. t+18) -> f16 chunk buffer
      const int uu = tid - 256;
      const float4 v = *(const float4*)&s_xraw[4 * uu];
      const int nb = ((t + 3) >> 4) & 1;
      s_xh2[nb][2 * uu]     = pk2i(v.x, v.y);
      s_xh2[nb][2 * uu + 1] = pk2i(v.z, v.w);
    }

    const float xacc = s_xp[(t >> 4) & 1][tl][tid];

    // ---- dot streams (gate `g` of L0 col u and L1 col u) ----
    int ia = 0, ia2 = 0, ib = 0, ib2 = 0, ic = 0, ic2 = 0;
#pragma unroll
    for (int j = 0; j < 32; j += 2) {  // h0 -> w0h (g0) and w1x (g1)
      const int s0 = __builtin_amdgcn_readlane(vq, j);
      const int s1 = __builtin_amdgcn_readlane(vq, j + 1);
      ia  = sdot4(s0, q0h[j], ia);
      ib  = sdot4(s0, q1x[j], ib);
      ia2 = sdot4(s1, q0h[j + 1], ia2);
      ib2 = sdot4(s1, q1x[j + 1], ib2);
    }
#pragma unroll
    for (int j = 0; j < 32; j += 2) {  // h1 -> w1h (g1)
      const int s0 = __builtin_amdgcn_readlane(vq, 32 + j);
      const int s1 = __builtin_amdgcn_readlane(vq, 33 + j);
      ic  = sdot4(s0, q1h[j], ic);
      ic2 = sdot4(s1, q1h[j + 1], ic2);
    }
    const float g0v = bias0 + xacc + (float)(ia + ia2) * s0h;
    const float g1v = bias1 + (float)(ib + ib2) * s1x + (float)(ic + ic2) * s1h;

    // ---- in-quad gate collect (no barrier) ----
    const float Ai = bperm_f(pb,      g0v);
    const float Af = bperm_f(pb + 4,  g0v);
    const float Ag = bperm_f(pb + 8,  g0v);
    const float Ao = bperm_f(pb + 12, g0v);
    const float Bi = bperm_f(pb,      g1v);
    const float Bf = bperm_f(pb + 4,  g1v);
    const float Bg = bperm_f(pb + 8,  g1v);
    const float Bo = bperm_f(pb + 12, g1v);

    // ---- cell updates (quad-redundant), i8 h bytes to next-parity stash ----
    if (t < len) {
      c0 = sigm(Af) * c0 + sigm(Ai) * tanha(Ag);
      const float h0 = sigm(Ao) * tanha(c0);
      if (g == 0)
        ((signed char*)&s_hq[(t + 1) & 1][0])[u] =
            (signed char)(int)__builtin_rintf(h0 * 127.f);
    }
    if (t > 0) {
      c1 = sigm(Bf) * c1 + sigm(Bi) * tanha(Bg);
      const float h1 = sigm(Bo) * tanha(c1);
      if (g == 1)
        ((signed char*)&s_hq[(t + 1) & 1][0])[128 + u] =
            (signed char)(int)__builtin_rintf(h1 * 127.f);
      if (g == 2 && t == len) s_h1f[u] = h1;  // final fp32 h1(len-1)
    }

    if (tl == 14) burst(((t + 2) >> 4) & 1);  // project next chunk (1/16)
    __syncthreads();
  }

  // ---- LayerNorm over H on wave 0 ----
  if (tid < 64) {
    const float a = s_h1f[tid], d = s_h1f[64 + tid];
    float s = a + d, q = a * a + d * d;
#pragma unroll
    for (int m = 32; m >= 1; m >>= 1) {
      s += __shfl_xor(s, m, 64);
      q += __shfl_xor(q, m, 64);
    }
    const float mu = s * (1.f / 128.f);
    float var = q * (1.f / 128.f) - mu * mu;
    var = fmaxf(var, 0.f);
    const float rstd = rsqrtf(var + 1e-5f);
    s_hn[tid]      = (a - mu) * rstd * gam[tid]      + bet[tid];
    s_hn[64 + tid] = (d - mu) * rstd * gam[64 + tid] + bet[64 + tid];
  }
  __syncthreads();

  // ---- FC head ----
  if (tid < Cn) {
    float acc = fcb[tid];
    const float* wp = fcw + tid * Hn;
#pragma unroll 4
    for (int k = 0; k < Hn; ++k) acc += s_hn[k] * wp[k];
    out[(size_t)b * Cn + tid] = acc;
  }
}

extern "C" void kernel_launch(void* const* d_in, const int* in_sizes, int n_in,
                              void* d_out, int out_size, void* d_ws, size_t ws_size,
                              hipStream_t stream) {
  (void)in_sizes; (void)n_in; (void)d_ws; (void)ws_size; (void)out_size;
  lstm2_fused<<<dim3(Bn), dim3(512), 0, stream>>>(
      (const float*)d_in[0],  (const int*)d_in[1],
      (const float*)d_in[2],  (const float*)d_in[3],
      (const float*)d_in[4],  (const float*)d_in[5],
      (const float*)d_in[6],  (const float*)d_in[7],
      (const float*)d_in[8],  (const float*)d_in[9],
      (const float*)d_in[10], (const float*)d_in[11],
      (const float*)d_in[12], (const float*)d_in[13],
      (float*)d_out);
}